// Round 7
// baseline (1156.587 us; speedup 1.0000x reference)
//
#include <hip/hip_runtime.h>
#include <hip/hip_bf16.h>

#define NN 20000
#define EE 160000

typedef __attribute__((ext_vector_type(8))) short bf16x8;
typedef __attribute__((ext_vector_type(4))) float f32x4;

__device__ __forceinline__ unsigned short f2bf(float f) {
    unsigned int u = __float_as_uint(f);
    u += 0x7FFFu + ((u >> 16) & 1);   // RNE
    return (unsigned short)(u >> 16);
}
__device__ __forceinline__ float bf2f(short s) {
    return __uint_as_float(((unsigned int)(unsigned short)s) << 16);
}
__device__ __forceinline__ bf16x8 pack8(float4 a, float4 b) {
    bf16x8 r;
    r[0] = (short)f2bf(a.x); r[1] = (short)f2bf(a.y);
    r[2] = (short)f2bf(a.z); r[3] = (short)f2bf(a.w);
    r[4] = (short)f2bf(b.x); r[5] = (short)f2bf(b.y);
    r[6] = (short)f2bf(b.z); r[7] = (short)f2bf(b.w);
    return r;
}

#define SH_STRIDE 136   // bf16 elems/row
#define ROWS_PB 64      // 4 waves x 16 rows

// MFMA sweep over 8 col-tiles, ONE row-tile (acc = 32 VGPRs/wave)
__device__ __forceinline__ void mfma_sweep1(f32x4 (&acc)[8], bf16x8 a,
                                            const short* __restrict__ Wt, int Kpad,
                                            int kb, int lm)
{
#pragma unroll
    for (int ct = 0; ct < 8; ++ct) {
        bf16x8 b = *(const bf16x8*)(Wt + (size_t)(ct * 16 + lm) * Kpad + kb);
        acc[ct] = __builtin_amdgcn_mfma_f32_16x16x32_bf16(a, b, acc[ct], 0, 0, 0);
    }
}

__device__ __forceinline__ void zero_acc1(f32x4 (&acc)[8]) {
#pragma unroll
    for (int j = 0; j < 8; ++j) acc[j] = (f32x4)(0.f);
}

// park acc -> sH as bf16 with bias+relu (wave-private 16 rows)
__device__ __forceinline__ void park1(const f32x4 (&acc)[8], const float* __restrict__ bias,
                                      short* __restrict__ sH, int w16, int lm, int lq)
{
#pragma unroll
    for (int ct = 0; ct < 8; ++ct) {
        float bb = bias[ct * 16 + lm];
#pragma unroll
        for (int reg = 0; reg < 4; ++reg) {
            float v = fmaxf(acc[ct][reg] + bb, 0.f);
            sH[(w16 + lq * 4 + reg) * SH_STRIDE + ct * 16 + lm] = (short)f2bf(v);
        }
    }
}

// modes: 0 = encoder (stage fp32 A0f K0<=32); 1 = edge gather (nfb,nfb,ef) sorted by eList;
//        2 = node concat (nfb, agg fp32); 3 = decoder (nfb; tail 128->3)
__global__ __launch_bounds__(256) void gnn_mlp(
    const short* __restrict__ Wt0, int Kpad0,
    const short* __restrict__ Wt1, const short* __restrict__ Wt2,
    const float* __restrict__ b0, const float* __restrict__ b1, const float* __restrict__ b2,
    const float* __restrict__ g, const float* __restrict__ be,
    const float* __restrict__ A0f, int K0,          // mode0: src; mode3: dec_W2 [128x3]
    const short* __restrict__ nfb,
    const float* __restrict__ eff,                  // mode1: ef fp32 (seg2 + residual)
    const float* __restrict__ aggf,                 // mode2: agg fp32
    const int* __restrict__ eList,                  // mode1: sorted edge ids (or null)
    const int* __restrict__ senders, const int* __restrict__ receivers,
    float* __restrict__ outF, short* __restrict__ outB,
    float* __restrict__ aggOut,                     // mode1: fp32 atomic dest
    float* __restrict__ decOut,
    int M, int mode, int resid)
{
    __shared__ short sH[ROWS_PB * SH_STRIDE];
    __shared__ int sEdge[ROWS_PB], sRcv[ROWS_PB], sSnd[ROWS_PB];
    const int tid = threadIdx.x;
    const int lane = tid & 63;
    const int w = tid >> 6;           // wave 0..3
    const int lm = lane & 15;
    const int lq = lane >> 4;
    const int w16 = w * 16;
    const int m0 = blockIdx.x * ROWS_PB;

    if (mode == 1) {
        if (tid < ROWS_PB) {
            int slot = m0 + tid;                       // grid exact: slot < E
            int e = eList ? eList[slot] : slot;
            sEdge[tid] = e;
            sRcv[tid] = receivers[e];
            sSnd[tid] = senders[e];
        }
        __syncthreads();
    }

    f32x4 acc[8];
    zero_acc1(acc);

    // -------- layer 0 --------
    if (mode == 0) {
        // stage this wave's 16 rows x 32 k (zero-padded) as bf16
#pragma unroll
        for (int i = 0; i < 8; ++i) {
            int flat = lane + i * 64;                  // 0..511 = 16 rows x 32 k
            int r = flat >> 5, k = flat & 31;
            int row = m0 + w16 + r;
            float v = (k < K0 && row < M) ? A0f[(size_t)row * K0 + k] : 0.f;
            sH[(w16 + r) * SH_STRIDE + k] = (short)f2bf(v);
        }
        bf16x8 a = *(const bf16x8*)&sH[(w16 + lm) * SH_STRIDE + lq * 8];
        mfma_sweep1(acc, a, Wt0, Kpad0, lq * 8, lm);
    } else if (mode == 1) {
        int e0  = sEdge[w16 + lm];
        int s0a = sSnd[w16 + lm];
        int s1a = sRcv[w16 + lm];
#pragma unroll
        for (int c = 0; c < 4; ++c) {   // seg 0: nf[senders]
            int kb = c * 32 + lq * 8;
            bf16x8 a = *(const bf16x8*)(nfb + (size_t)s0a * 128 + kb);
            mfma_sweep1(acc, a, Wt0, Kpad0, c * 32 + lq * 8, lm);
        }
#pragma unroll
        for (int c = 0; c < 4; ++c) {   // seg 1: nf[receivers]
            int kb = c * 32 + lq * 8;
            bf16x8 a = *(const bf16x8*)(nfb + (size_t)s1a * 128 + kb);
            mfma_sweep1(acc, a, Wt0, Kpad0, 128 + c * 32 + lq * 8, lm);
        }
#pragma unroll
        for (int c = 0; c < 4; ++c) {   // seg 2: ef (fp32 -> bf16)
            int kb = c * 32 + lq * 8;
            const float* p0 = eff + (size_t)e0 * 128 + kb;
            bf16x8 a = pack8(*(const float4*)p0, *(const float4*)(p0 + 4));
            mfma_sweep1(acc, a, Wt0, Kpad0, 256 + c * 32 + lq * 8, lm);
        }
    } else if (mode == 2) {
        int r0 = min(m0 + w16 + lm, M - 1);
#pragma unroll
        for (int c = 0; c < 4; ++c) {   // seg 0: nf
            int kb = c * 32 + lq * 8;
            bf16x8 a = *(const bf16x8*)(nfb + (size_t)r0 * 128 + kb);
            mfma_sweep1(acc, a, Wt0, Kpad0, c * 32 + lq * 8, lm);
        }
#pragma unroll
        for (int c = 0; c < 4; ++c) {   // seg 1: agg (fp32 -> bf16)
            int kb = c * 32 + lq * 8;
            const float* p0 = aggf + (size_t)r0 * 128 + kb;
            bf16x8 a = pack8(*(const float4*)p0, *(const float4*)(p0 + 4));
            mfma_sweep1(acc, a, Wt0, Kpad0, 128 + c * 32 + lq * 8, lm);
        }
    } else {  // mode 3: decoder
        int r0 = min(m0 + w16 + lm, M - 1);
#pragma unroll
        for (int c = 0; c < 4; ++c) {
            int kb = c * 32 + lq * 8;
            bf16x8 a = *(const bf16x8*)(nfb + (size_t)r0 * 128 + kb);
            mfma_sweep1(acc, a, Wt0, Kpad0, c * 32 + lq * 8, lm);
        }
    }
    park1(acc, b0, sH, w16, lm, lq);   // h1 (relu) -> LDS, wave-private rows

    // -------- layer 1 --------
    zero_acc1(acc);
#pragma unroll
    for (int c = 0; c < 4; ++c) {
        int kb = c * 32 + lq * 8;
        bf16x8 a = *(const bf16x8*)&sH[(w16 + lm) * SH_STRIDE + kb];
        mfma_sweep1(acc, a, Wt1, 128, kb, lm);
    }
    park1(acc, b1, sH, w16, lm, lq);

    // -------- decoder tail: h2 @ dec_W2[128x3] + b2 --------
    if (mode == 3) {
        if (lane < 48) {                               // 16 rows x 3 outs per wave
            int r = lane / 3, o = lane - r * 3;
            int row = m0 + w16 + r;
            if (row < M) {
                float s = b2[o];
#pragma unroll
                for (int kk = 0; kk < 16; ++kk) {
                    bf16x8 h8 = *(const bf16x8*)&sH[(w16 + r) * SH_STRIDE + kk * 8];
#pragma unroll
                    for (int j = 0; j < 8; ++j)
                        s += bf2f(h8[j]) * A0f[(kk * 8 + j) * 3 + o];
                }
                decOut[(size_t)row * 3 + o] = s;
            }
        }
        return;
    }

    // -------- layer 2 --------
    zero_acc1(acc);
#pragma unroll
    for (int c = 0; c < 4; ++c) {
        int kb = c * 32 + lq * 8;
        bf16x8 a = *(const bf16x8*)&sH[(w16 + lm) * SH_STRIDE + kb];
        mfma_sweep1(acc, a, Wt2, 128, kb, lm);
    }

    // -------- epilogue: bias + LN (+ residual / shadow / merged scatter) --------
    float g_[8], be_[8], b2_[8];
#pragma unroll
    for (int ct = 0; ct < 8; ++ct) {
        g_[ct] = g[ct * 16 + lm]; be_[ct] = be[ct * 16 + lm]; b2_[ct] = b2[ct * 16 + lm];
    }

    if (mode == 1) {
        // rows = sorted edge slots; merge same-receiver runs in registers
        float run[8];
        int curRcv = -1;
#pragma unroll
        for (int reg = 0; reg < 4; ++reg) {
            int rloc = w16 + lq * 4 + reg;             // consecutive sorted slots
            float v[8];
            float s = 0.f;
#pragma unroll
            for (int ct = 0; ct < 8; ++ct) { v[ct] = acc[ct][reg] + b2_[ct]; s += v[ct]; }
            s += __shfl_xor(s, 1); s += __shfl_xor(s, 2);
            s += __shfl_xor(s, 4); s += __shfl_xor(s, 8);
            float mu = s * (1.f / 128.f);
            float q = 0.f;
#pragma unroll
            for (int ct = 0; ct < 8; ++ct) { v[ct] -= mu; q += v[ct] * v[ct]; }
            q += __shfl_xor(q, 1); q += __shfl_xor(q, 2);
            q += __shfl_xor(q, 4); q += __shfl_xor(q, 8);
            float rs = rsqrtf(q * (1.f / 128.f) + 1e-5f);
            int e = sEdge[rloc];
            int rcv = sRcv[rloc];
            float o[8];
#pragma unroll
            for (int ct = 0; ct < 8; ++ct) {
                o[ct] = v[ct] * rs * g_[ct] + be_[ct];
                size_t gi = (size_t)e * 128 + ct * 16 + lm;
                outF[gi] += o[ct];                      // ef residual
            }
            if (rcv != curRcv) {
                if (curRcv >= 0) {
#pragma unroll
                    for (int ct = 0; ct < 8; ++ct)
                        atomicAdd(aggOut + (size_t)curRcv * 128 + ct * 16 + lm, run[ct]);
                }
                curRcv = rcv;
#pragma unroll
                for (int ct = 0; ct < 8; ++ct) run[ct] = o[ct];
            } else {
#pragma unroll
                for (int ct = 0; ct < 8; ++ct) run[ct] += o[ct];
            }
        }
        if (curRcv >= 0) {
#pragma unroll
            for (int ct = 0; ct < 8; ++ct)
                atomicAdd(aggOut + (size_t)curRcv * 128 + ct * 16 + lm, run[ct]);
        }
    } else {
#pragma unroll
        for (int reg = 0; reg < 4; ++reg) {
            int row = m0 + w16 + lq * 4 + reg;
            float v[8];
            float s = 0.f;
#pragma unroll
            for (int ct = 0; ct < 8; ++ct) { v[ct] = acc[ct][reg] + b2_[ct]; s += v[ct]; }
            s += __shfl_xor(s, 1); s += __shfl_xor(s, 2);
            s += __shfl_xor(s, 4); s += __shfl_xor(s, 8);
            float mu = s * (1.f / 128.f);
            float q = 0.f;
#pragma unroll
            for (int ct = 0; ct < 8; ++ct) { v[ct] -= mu; q += v[ct] * v[ct]; }
            q += __shfl_xor(q, 1); q += __shfl_xor(q, 2);
            q += __shfl_xor(q, 4); q += __shfl_xor(q, 8);
            float rs = rsqrtf(q * (1.f / 128.f) + 1e-5f);
            if (row < M) {
#pragma unroll
                for (int ct = 0; ct < 8; ++ct) {
                    float o = v[ct] * rs * g_[ct] + be_[ct];
                    size_t gi = (size_t)row * 128 + ct * 16 + lm;
                    if (resid) {
                        float ns = outF[gi] + o;
                        outF[gi] = ns;
                        if (outB) outB[gi] = (short)f2bf(ns);
                    } else {
                        outF[gi] = o;
                        if (outB) outB[gi] = (short)f2bf(o);
                    }
                }
            }
        }
    }
}

// ---------------------------------------------------------------------------
// counting-sort of edges by receiver: cnt -> exclusive-prefix cursor -> fill
// ---------------------------------------------------------------------------
__global__ void zero_i(int* __restrict__ p, int n)
{
    int i = blockIdx.x * 256 + threadIdx.x;
    if (i < n) p[i] = 0;
}
__global__ void csr_count(const int* __restrict__ recv, int* __restrict__ cnt, int E)
{
    int i = blockIdx.x * 256 + threadIdx.x;
    if (i < E) atomicAdd(&cnt[recv[i]], 1);
}
__global__ __launch_bounds__(256) void csr_scan(const int* __restrict__ cnt,
                                                int* __restrict__ cursor, int N)
{
    __shared__ int ssum[257];
    const int tid = threadIdx.x;
    const int per = (N + 255) / 256;
    const int lo = tid * per, hi = min(lo + per, N);
    int s = 0;
    for (int i = lo; i < hi; ++i) s += cnt[i];
    ssum[tid] = s;
    __syncthreads();
    if (tid == 0) {
        int run = 0;
        for (int i = 0; i < 256; ++i) { int t = ssum[i]; ssum[i] = run; run += t; }
        ssum[256] = run;
    }
    __syncthreads();
    int run = ssum[tid];
    for (int i = lo; i < hi; ++i) { int c = cnt[i]; cursor[i] = run; run += c; }
}
__global__ void csr_fill(const int* __restrict__ recv, int* __restrict__ cursor,
                         int* __restrict__ eList, int E)
{
    int i = blockIdx.x * 256 + threadIdx.x;
    if (i < E) {
        int pos = atomicAdd(&cursor[recv[i]], 1);
        eList[pos] = i;
    }
}

// ---------------------------------------------------------------------------
struct WtPrep { const float* src; int K; int Kpad; int dstOff; };
struct WtPrepAll { WtPrep m[26]; };

__global__ void wt_prep_kernel(WtPrepAll all, short* __restrict__ dst)
{
    const WtPrep p = all.m[blockIdx.y];
    int total = 128 * p.Kpad;
    int idx = blockIdx.x * 256 + threadIdx.x;
    if (idx >= total) return;
    int n = idx / p.Kpad, k = idx - n * p.Kpad;
    float v = (k < p.K) ? p.src[(size_t)k * 128 + n] : 0.f;
    dst[p.dstOff + idx] = (short)f2bf(v);
}

__global__ void zero_kernel(float4* __restrict__ p, long n4)
{
    long i = (long)blockIdx.x * blockDim.x + threadIdx.x;
    if (i < n4) p[i] = make_float4(0.f, 0.f, 0.f, 0.f);
}

// ---------------------------------------------------------------------------
extern "C" void kernel_launch(void* const* d_in, const int* in_sizes, int n_in,
                              void* d_out, int out_size, void* d_ws, size_t ws_size,
                              hipStream_t stream)
{
    const float* node_x   = (const float*)d_in[0];
    const float* edge_x   = (const float*)d_in[1];
    const float* enc_n_W0 = (const float*)d_in[2];
    const float* enc_n_b0 = (const float*)d_in[3];
    const float* enc_n_W1 = (const float*)d_in[4];
    const float* enc_n_b1 = (const float*)d_in[5];
    const float* enc_n_W2 = (const float*)d_in[6];
    const float* enc_n_b2 = (const float*)d_in[7];
    const float* enc_n_g  = (const float*)d_in[8];
    const float* enc_n_be = (const float*)d_in[9];
    const float* enc_e_W0 = (const float*)d_in[10];
    const float* enc_e_b0 = (const float*)d_in[11];
    const float* enc_e_W1 = (const float*)d_in[12];
    const float* enc_e_b1 = (const float*)d_in[13];
    const float* enc_e_W2 = (const float*)d_in[14];
    const float* enc_e_b2 = (const float*)d_in[15];
    const float* enc_e_g  = (const float*)d_in[16];
    const float* enc_e_be = (const float*)d_in[17];
    const float* gnb_e_W0 = (const float*)d_in[18];
    const float* gnb_e_b0 = (const float*)d_in[19];
    const float* gnb_e_W1 = (const float*)d_in[20];
    const float* gnb_e_b1 = (const float*)d_in[21];
    const float* gnb_e_W2 = (const float*)d_in[22];
    const float* gnb_e_b2 = (const float*)d_in[23];
    const float* gnb_e_g  = (const float*)d_in[24];
    const float* gnb_e_be = (const float*)d_in[25];
    const float* gnb_n_W0 = (const float*)d_in[26];
    const float* gnb_n_b0 = (const float*)d_in[27];
    const float* gnb_n_W1 = (const float*)d_in[28];
    const float* gnb_n_b1 = (const float*)d_in[29];
    const float* gnb_n_W2 = (const float*)d_in[30];
    const float* gnb_n_b2 = (const float*)d_in[31];
    const float* gnb_n_g  = (const float*)d_in[32];
    const float* gnb_n_be = (const float*)d_in[33];
    const float* dec_W0   = (const float*)d_in[34];
    const float* dec_b0   = (const float*)d_in[35];
    const float* dec_W1   = (const float*)d_in[36];
    const float* dec_b1   = (const float*)d_in[37];
    const float* dec_W2   = (const float*)d_in[38];
    const float* dec_b2   = (const float*)d_in[39];
    const int*   senders  = (const int*)d_in[40];
    const int*   receivers= (const int*)d_in[41];
    float* out = (float*)d_out;

    const int N = NN, E = EE;
    const int WT_TOTAL = (32 + 128 + 128 + 32 + 128 + 128 + 3 * (384 + 128 + 128 + 256 + 128 + 128)
                          + 128 + 128) * 128;   // shorts = 548864

    // ---- workspace layout: identical to round 6 (109.26 MB, known-good) ----
    float* nf   = (float*)d_ws;                      // N*128 f32
    float* agg  = nf + (size_t)N * 128;              // N*128 f32
    float* ef   = agg + (size_t)N * 128;             // E*128 f32
    short* nfbf = (short*)(ef + (size_t)E * 128);    // N*128 bf16
    short* wt   = nfbf + (size_t)N * 128;            // WT_TOTAL bf16
    int*   eList = (int*)(wt + WT_TOTAL);            // E ints (sorted path only)
    size_t need_sorted = (size_t)((char*)(eList + E) - (char*)d_ws);
    int* cnt    = (int*)agg;                          // transient overlay on agg
    int* cursor = cnt + N;

    const bool useSorted = (ws_size >= need_sorted);
    const int* eL = useSorted ? eList : nullptr;

    // ---- weight prep table ----
    WtPrepAll tbl;
    int nMat = 0, off = 0;
    int o_encn[3], o_ence[3], o_ge0[3], o_ge1[3], o_ge2[3], o_gn0[3], o_gn1[3], o_gn2[3], o_dec[2];
    auto add = [&](const float* src, int K, int Kpad) {
        tbl.m[nMat].src = src; tbl.m[nMat].K = K; tbl.m[nMat].Kpad = Kpad;
        tbl.m[nMat].dstOff = off;
        int r = off; off += 128 * Kpad; ++nMat; return r;
    };
    o_encn[0] = add(enc_n_W0, 12, 32);
    o_encn[1] = add(enc_n_W1, 128, 128);
    o_encn[2] = add(enc_n_W2, 128, 128);
    o_ence[0] = add(enc_e_W0, 7, 32);
    o_ence[1] = add(enc_e_W1, 128, 128);
    o_ence[2] = add(enc_e_W2, 128, 128);
    for (int s = 0; s < 3; ++s) {
        o_ge0[s] = add(gnb_e_W0 + (size_t)s * 384 * 128, 384, 384);
        o_ge1[s] = add(gnb_e_W1 + (size_t)s * 128 * 128, 128, 128);
        o_ge2[s] = add(gnb_e_W2 + (size_t)s * 128 * 128, 128, 128);
        o_gn0[s] = add(gnb_n_W0 + (size_t)s * 256 * 128, 256, 256);
        o_gn1[s] = add(gnb_n_W1 + (size_t)s * 128 * 128, 128, 128);
        o_gn2[s] = add(gnb_n_W2 + (size_t)s * 128 * 128, 128, 128);
    }
    o_dec[0] = add(dec_W0, 128, 128);
    o_dec[1] = add(dec_W1, 128, 128);

    wt_prep_kernel<<<dim3(192, 26), 256, 0, stream>>>(tbl, wt);

    if (useSorted) {
        zero_i<<<dim3((N + 255) / 256), 256, 0, stream>>>(cnt, N);
        csr_count<<<dim3((E + 255) / 256), 256, 0, stream>>>(receivers, cnt, E);
        csr_scan<<<dim3(1), 256, 0, stream>>>(cnt, cursor, N);
        csr_fill<<<dim3((E + 255) / 256), 256, 0, stream>>>(receivers, cursor, eList, E);
    }

    const dim3 gN((N + ROWS_PB - 1) / ROWS_PB), gE(E / ROWS_PB);

    // ---- encoders ----
    gnn_mlp<<<gN, 256, 0, stream>>>(wt + o_encn[0], 32, wt + o_encn[1], wt + o_encn[2],
        enc_n_b0, enc_n_b1, enc_n_b2, enc_n_g, enc_n_be,
        node_x, 12, nullptr, nullptr, nullptr, nullptr, nullptr, nullptr,
        nf, nfbf, nullptr, nullptr, N, 0, 0);
    gnn_mlp<<<gE, 256, 0, stream>>>(wt + o_ence[0], 32, wt + o_ence[1], wt + o_ence[2],
        enc_e_b0, enc_e_b1, enc_e_b2, enc_e_g, enc_e_be,
        edge_x, 7, nullptr, nullptr, nullptr, nullptr, nullptr, nullptr,
        ef, nullptr, nullptr, nullptr, E, 0, 0);

    // ---- 3 message-passing steps ----
    for (int s = 0; s < 3; ++s) {
        const float* eb0 = gnb_e_b0 + (size_t)s * 128;
        const float* eb1 = gnb_e_b1 + (size_t)s * 128;
        const float* eb2 = gnb_e_b2 + (size_t)s * 128;
        const float* eg  = gnb_e_g  + (size_t)s * 128;
        const float* ebe = gnb_e_be + (size_t)s * 128;
        const float* nb0 = gnb_n_b0 + (size_t)s * 128;
        const float* nb1 = gnb_n_b1 + (size_t)s * 128;
        const float* nb2 = gnb_n_b2 + (size_t)s * 128;
        const float* ng  = gnb_n_g  + (size_t)s * 128;
        const float* nbe = gnb_n_be + (size_t)s * 128;

        zero_kernel<<<dim3((N * 32 + 255) / 256), 256, 0, stream>>>((float4*)agg, (long)N * 32);
        gnn_mlp<<<gE, 256, 0, stream>>>(wt + o_ge0[s], 384, wt + o_ge1[s], wt + o_ge2[s],
            eb0, eb1, eb2, eg, ebe,
            nullptr, 0, nfbf, ef, nullptr, eL, senders, receivers,
            ef, nullptr, agg, nullptr, E, 1, 1);
        gnn_mlp<<<gN, 256, 0, stream>>>(wt + o_gn0[s], 256, wt + o_gn1[s], wt + o_gn2[s],
            nb0, nb1, nb2, ng, nbe,
            nullptr, 0, nfbf, nullptr, agg, nullptr, nullptr, nullptr,
            nf, nfbf, nullptr, nullptr, N, 2, 1);
    }

    // ---- decoder ----
    gnn_mlp<<<gN, 256, 0, stream>>>(wt + o_dec[0], 128, wt + o_dec[1], nullptr,
        dec_b0, dec_b1, dec_b2, nullptr, nullptr,
        dec_W2, 0, nfbf, nullptr, nullptr, nullptr, nullptr, nullptr,
        nullptr, nullptr, nullptr, out, N, 3, 0);
}

// Round 8
// 769.969 us; speedup vs baseline: 1.5021x; 1.5021x over previous
//
#include <hip/hip_runtime.h>
#include <hip/hip_bf16.h>

#define NN 20000
#define EE 160000

typedef __attribute__((ext_vector_type(8))) short bf16x8;
typedef __attribute__((ext_vector_type(4))) float f32x4;

__device__ __forceinline__ unsigned short f2bf(float f) {
    unsigned int u = __float_as_uint(f);
    u += 0x7FFFu + ((u >> 16) & 1);   // RNE
    return (unsigned short)(u >> 16);
}
__device__ __forceinline__ float bf2f(short s) {
    return __uint_as_float(((unsigned int)(unsigned short)s) << 16);
}
__device__ __forceinline__ bf16x8 pack8(float4 a, float4 b) {
    bf16x8 r;
    r[0] = (short)f2bf(a.x); r[1] = (short)f2bf(a.y);
    r[2] = (short)f2bf(a.z); r[3] = (short)f2bf(a.w);
    r[4] = (short)f2bf(b.x); r[5] = (short)f2bf(b.y);
    r[6] = (short)f2bf(b.z); r[7] = (short)f2bf(b.w);
    return r;
}

#define SH_STRIDE 136   // bf16 elems/row (sH)
#define SW_STRIDE 40    // bf16 elems/row (sW chunk: 32 k + 8 pad = 80 B, 16B-aligned)

// MFMA sweep: B fragments from LDS chunk (ds_read_b128), 2 row-tiles x 8 col-tiles
__device__ __forceinline__ void mfma_sweep_lds(f32x4 (&acc)[2][8], bf16x8 a0, bf16x8 a1,
                                               const short* sWb, int lm, int lq)
{
#pragma unroll
    for (int ct = 0; ct < 8; ++ct) {
        bf16x8 b = *(const bf16x8*)(sWb + (ct * 16 + lm) * SW_STRIDE + lq * 8);
        acc[0][ct] = __builtin_amdgcn_mfma_f32_16x16x32_bf16(a0, b, acc[0][ct], 0, 0, 0);
        acc[1][ct] = __builtin_amdgcn_mfma_f32_16x16x32_bf16(a1, b, acc[1][ct], 0, 0, 0);
    }
}

// cooperative stage of one 128x32 weight chunk into sW (256 threads: row=tid/2, half=tid&1)
__device__ __forceinline__ void stage_w(short* __restrict__ sW, const short* __restrict__ Wt,
                                        int Kpad, int k0, int tid)
{
    int r = tid >> 1, h = tid & 1;
    const short* src = Wt + (size_t)r * Kpad + k0 + h * 16;
    short* dst = sW + r * SW_STRIDE + h * 16;
    *(bf16x8*)dst       = *(const bf16x8*)src;
    *(bf16x8*)(dst + 8) = *(const bf16x8*)(src + 8);
}

__device__ __forceinline__ void zero_acc(f32x4 (&acc)[2][8]) {
#pragma unroll
    for (int i = 0; i < 2; ++i)
#pragma unroll
        for (int j = 0; j < 8; ++j) acc[i][j] = (f32x4)(0.f);
}

__device__ __forceinline__ void park(const f32x4 (&acc)[2][8], const float* __restrict__ bias,
                                     short* __restrict__ sH, int w32, int lm, int lq)
{
#pragma unroll
    for (int ct = 0; ct < 8; ++ct) {
        float bb = bias[ct * 16 + lm];
#pragma unroll
        for (int rt = 0; rt < 2; ++rt) {
            int rbase = w32 + rt * 16 + lq * 4;
#pragma unroll
            for (int reg = 0; reg < 4; ++reg) {
                float v = fmaxf(acc[rt][ct][reg] + bb, 0.f);
                sH[(rbase + reg) * SH_STRIDE + ct * 16 + lm] = (short)f2bf(v);
            }
        }
    }
}

// modes: 0 = encoder (stage fp32 A0f K0<=32); 1 = edge gather (nfb,nfb,ef) sorted by eList;
//        2 = node concat (nfb, agg fp32); 3 = decoder (nfb; tail 128->3)
__global__ __launch_bounds__(256) void gnn_mlp(
    const short* __restrict__ Wt0, int Kpad0,
    const short* __restrict__ Wt1, const short* __restrict__ Wt2,
    const float* __restrict__ b0, const float* __restrict__ b1, const float* __restrict__ b2,
    const float* __restrict__ g, const float* __restrict__ be,
    const float* __restrict__ A0f, int K0,          // mode0: src; mode3: dec_W2 [128x3]
    const short* __restrict__ nfb,
    const float* __restrict__ eff,                  // mode1: ef fp32 (seg2 + residual)
    const float* __restrict__ aggf,                 // mode2: agg fp32
    const int* __restrict__ eList,                  // mode1: sorted edge ids (or null)
    const int* __restrict__ senders, const int* __restrict__ receivers,
    float* __restrict__ outF, short* __restrict__ outB,
    float* __restrict__ aggOut,                     // mode1: fp32 atomic dest
    float* __restrict__ decOut,
    int M, int mode, int resid)
{
    __shared__ short sH[128 * SH_STRIDE];
    __shared__ short sW[128 * SW_STRIDE];
    __shared__ int sEdge[128], sRcv[128], sSnd[128];
    const int tid = threadIdx.x;
    const int lane = tid & 63;
    const int w = tid >> 6;           // wave 0..3
    const int lm = lane & 15;
    const int lq = lane >> 4;
    const int w32 = w * 32;
    const int m0 = blockIdx.x * 128;

    if (mode == 1) {
        if (tid < 128) {
            int slot = m0 + tid;                       // grid exact: slot < E
            int e = eList ? eList[slot] : slot;
            sEdge[tid] = e;
            sRcv[tid] = receivers[e];
            sSnd[tid] = senders[e];
        }
        __syncthreads();
    }

    f32x4 acc[2][8];
    zero_acc(acc);

    // -------- layer 0 --------
    if (mode == 0) {
        // stage 32 rows x 32 k per wave (zero-padded) into sH as bf16
#pragma unroll
        for (int i = 0; i < 16; ++i) {
            int flat = lane + i * 64;                  // 0..1023 = 32 rows x 32 k
            int r = flat >> 5, k = flat & 31;
            int row = m0 + w32 + r;
            float v = (k < K0 && row < M) ? A0f[(size_t)row * K0 + k] : 0.f;
            sH[(w32 + r) * SH_STRIDE + k] = (short)f2bf(v);
        }
    }
    const int r0m = min(m0 + w32 + lm, M - 1);         // modes 2/3
    const int r1m = min(m0 + w32 + 16 + lm, M - 1);
    const int nC0 = Kpad0 >> 5;
    for (int c = 0; c < nC0; ++c) {
        const int kq = lq * 8;
        bf16x8 a0, a1;
        if (mode == 0) {
            a0 = *(const bf16x8*)&sH[(w32 + lm) * SH_STRIDE + c * 32 + kq];
            a1 = *(const bf16x8*)&sH[(w32 + 16 + lm) * SH_STRIDE + c * 32 + kq];
        } else if (mode == 1) {
            int seg = c >> 2, kb = (c & 3) * 32 + kq;
            if (seg == 0) {
                a0 = *(const bf16x8*)(nfb + (size_t)sSnd[w32 + lm] * 128 + kb);
                a1 = *(const bf16x8*)(nfb + (size_t)sSnd[w32 + 16 + lm] * 128 + kb);
            } else if (seg == 1) {
                a0 = *(const bf16x8*)(nfb + (size_t)sRcv[w32 + lm] * 128 + kb);
                a1 = *(const bf16x8*)(nfb + (size_t)sRcv[w32 + 16 + lm] * 128 + kb);
            } else {
                const float* p0 = eff + (size_t)sEdge[w32 + lm] * 128 + kb;
                const float* p1 = eff + (size_t)sEdge[w32 + 16 + lm] * 128 + kb;
                a0 = pack8(*(const float4*)p0, *(const float4*)(p0 + 4));
                a1 = pack8(*(const float4*)p1, *(const float4*)(p1 + 4));
            }
        } else if (mode == 2) {
            int seg = c >> 2, kb = (c & 3) * 32 + kq;
            if (seg == 0) {
                a0 = *(const bf16x8*)(nfb + (size_t)r0m * 128 + kb);
                a1 = *(const bf16x8*)(nfb + (size_t)r1m * 128 + kb);
            } else {
                const float* p0 = aggf + (size_t)r0m * 128 + kb;
                const float* p1 = aggf + (size_t)r1m * 128 + kb;
                a0 = pack8(*(const float4*)p0, *(const float4*)(p0 + 4));
                a1 = pack8(*(const float4*)p1, *(const float4*)(p1 + 4));
            }
        } else {  // mode 3
            int kb = c * 32 + kq;
            a0 = *(const bf16x8*)(nfb + (size_t)r0m * 128 + kb);
            a1 = *(const bf16x8*)(nfb + (size_t)r1m * 128 + kb);
        }
        __syncthreads();                    // all waves done reading previous sW chunk
        stage_w(sW, Wt0, Kpad0, c * 32, tid);
        __syncthreads();                    // chunk staged (A-loads also drain here)
        mfma_sweep_lds(acc, a0, a1, sW, lm, lq);
    }
    park(acc, b0, sH, w32, lm, lq);   // h1 (relu) -> LDS, wave-private rows

    // -------- layer 1 --------
    zero_acc(acc);
    for (int c = 0; c < 4; ++c) {
        bf16x8 a0 = *(const bf16x8*)&sH[(w32 + lm) * SH_STRIDE + c * 32 + lq * 8];
        bf16x8 a1 = *(const bf16x8*)&sH[(w32 + 16 + lm) * SH_STRIDE + c * 32 + lq * 8];
        __syncthreads();
        stage_w(sW, Wt1, 128, c * 32, tid);
        __syncthreads();
        mfma_sweep_lds(acc, a0, a1, sW, lm, lq);
    }
    park(acc, b1, sH, w32, lm, lq);

    // -------- decoder tail: h2 @ dec_W2[128x3] + b2 --------
    if (mode == 3) {
#pragma unroll
        for (int t = 0; t < 2; ++t) {
            int idx = t * 64 + lane;
            if (idx < 96) {
                int r = idx / 3, o = idx - r * 3;
                int row = m0 + w32 + r;
                if (row < M) {
                    float s = b2[o];
#pragma unroll
                    for (int kk = 0; kk < 16; ++kk) {
                        bf16x8 h8 = *(const bf16x8*)&sH[(w32 + r) * SH_STRIDE + kk * 8];
#pragma unroll
                        for (int j = 0; j < 8; ++j)
                            s += bf2f(h8[j]) * A0f[(kk * 8 + j) * 3 + o];
                    }
                    decOut[(size_t)row * 3 + o] = s;
                }
            }
        }
        return;
    }

    // -------- layer 2 --------
    zero_acc(acc);
    for (int c = 0; c < 4; ++c) {
        bf16x8 a0 = *(const bf16x8*)&sH[(w32 + lm) * SH_STRIDE + c * 32 + lq * 8];
        bf16x8 a1 = *(const bf16x8*)&sH[(w32 + 16 + lm) * SH_STRIDE + c * 32 + lq * 8];
        __syncthreads();
        stage_w(sW, Wt2, 128, c * 32, tid);
        __syncthreads();
        mfma_sweep_lds(acc, a0, a1, sW, lm, lq);
    }

    // -------- epilogue: bias + LN (+ residual / shadow / merged scatter) --------
    float g_[8], be_[8], b2_[8];
#pragma unroll
    for (int ct = 0; ct < 8; ++ct) {
        g_[ct] = g[ct * 16 + lm]; be_[ct] = be[ct * 16 + lm]; b2_[ct] = b2[ct * 16 + lm];
    }

    if (mode == 1) {
        // rows = sorted edge slots; merge same-receiver runs in registers
#pragma unroll
        for (int rt = 0; rt < 2; ++rt) {
            float run[8];
            int curRcv = -1;
#pragma unroll
            for (int reg = 0; reg < 4; ++reg) {
                int rloc = w32 + rt * 16 + lq * 4 + reg;   // consecutive sorted slots
                float v[8];
                float s = 0.f;
#pragma unroll
                for (int ct = 0; ct < 8; ++ct) { v[ct] = acc[rt][ct][reg] + b2_[ct]; s += v[ct]; }
                s += __shfl_xor(s, 1); s += __shfl_xor(s, 2);
                s += __shfl_xor(s, 4); s += __shfl_xor(s, 8);
                float mu = s * (1.f / 128.f);
                float q = 0.f;
#pragma unroll
                for (int ct = 0; ct < 8; ++ct) { v[ct] -= mu; q += v[ct] * v[ct]; }
                q += __shfl_xor(q, 1); q += __shfl_xor(q, 2);
                q += __shfl_xor(q, 4); q += __shfl_xor(q, 8);
                float rs = rsqrtf(q * (1.f / 128.f) + 1e-5f);
                int e = sEdge[rloc];
                int rcv = sRcv[rloc];
                float o[8];
#pragma unroll
                for (int ct = 0; ct < 8; ++ct) {
                    o[ct] = v[ct] * rs * g_[ct] + be_[ct];
                    size_t gi = (size_t)e * 128 + ct * 16 + lm;
                    outF[gi] += o[ct];                      // ef residual
                }
                if (rcv != curRcv) {
                    if (curRcv >= 0) {
#pragma unroll
                        for (int ct = 0; ct < 8; ++ct)
                            atomicAdd(aggOut + (size_t)curRcv * 128 + ct * 16 + lm, run[ct]);
                    }
                    curRcv = rcv;
#pragma unroll
                    for (int ct = 0; ct < 8; ++ct) run[ct] = o[ct];
                } else {
#pragma unroll
                    for (int ct = 0; ct < 8; ++ct) run[ct] += o[ct];
                }
            }
            if (curRcv >= 0) {
#pragma unroll
                for (int ct = 0; ct < 8; ++ct)
                    atomicAdd(aggOut + (size_t)curRcv * 128 + ct * 16 + lm, run[ct]);
            }
        }
    } else {
#pragma unroll
        for (int rt = 0; rt < 2; ++rt) {
#pragma unroll
            for (int reg = 0; reg < 4; ++reg) {
                int row = m0 + w32 + rt * 16 + lq * 4 + reg;
                float v[8];
                float s = 0.f;
#pragma unroll
                for (int ct = 0; ct < 8; ++ct) { v[ct] = acc[rt][ct][reg] + b2_[ct]; s += v[ct]; }
                s += __shfl_xor(s, 1); s += __shfl_xor(s, 2);
                s += __shfl_xor(s, 4); s += __shfl_xor(s, 8);
                float mu = s * (1.f / 128.f);
                float q = 0.f;
#pragma unroll
                for (int ct = 0; ct < 8; ++ct) { v[ct] -= mu; q += v[ct] * v[ct]; }
                q += __shfl_xor(q, 1); q += __shfl_xor(q, 2);
                q += __shfl_xor(q, 4); q += __shfl_xor(q, 8);
                float rs = rsqrtf(q * (1.f / 128.f) + 1e-5f);
                if (row < M) {
#pragma unroll
                    for (int ct = 0; ct < 8; ++ct) {
                        float o = v[ct] * rs * g_[ct] + be_[ct];
                        size_t gi = (size_t)row * 128 + ct * 16 + lm;
                        if (resid) {
                            float ns = outF[gi] + o;
                            outF[gi] = ns;
                            if (outB) outB[gi] = (short)f2bf(ns);
                        } else {
                            outF[gi] = o;
                            if (outB) outB[gi] = (short)f2bf(o);
                        }
                    }
                }
            }
        }
    }
}

// ---------------------------------------------------------------------------
// counting-sort of edges by receiver: cnt -> exclusive-prefix cursor -> fill
// ---------------------------------------------------------------------------
__global__ void zero_i(int* __restrict__ p, int n)
{
    int i = blockIdx.x * 256 + threadIdx.x;
    if (i < n) p[i] = 0;
}
__global__ void csr_count(const int* __restrict__ recv, int* __restrict__ cnt, int E)
{
    int i = blockIdx.x * 256 + threadIdx.x;
    if (i < E) atomicAdd(&cnt[recv[i]], 1);
}
__global__ __launch_bounds__(256) void csr_scan(const int* __restrict__ cnt,
                                                int* __restrict__ cursor, int N)
{
    __shared__ int ssum[257];
    const int tid = threadIdx.x;
    const int per = (N + 255) / 256;
    const int lo = tid * per, hi = min(lo + per, N);
    int s = 0;
    for (int i = lo; i < hi; ++i) s += cnt[i];
    ssum[tid] = s;
    __syncthreads();
    if (tid == 0) {
        int run = 0;
        for (int i = 0; i < 256; ++i) { int t = ssum[i]; ssum[i] = run; run += t; }
        ssum[256] = run;
    }
    __syncthreads();
    int run = ssum[tid];
    for (int i = lo; i < hi; ++i) { int c = cnt[i]; cursor[i] = run; run += c; }
}
__global__ void csr_fill(const int* __restrict__ recv, int* __restrict__ cursor,
                         int* __restrict__ eList, int E)
{
    int i = blockIdx.x * 256 + threadIdx.x;
    if (i < E) {
        int pos = atomicAdd(&cursor[recv[i]], 1);
        eList[pos] = i;
    }
}

// ---------------------------------------------------------------------------
struct WtPrep { const float* src; int K; int Kpad; int dstOff; };
struct WtPrepAll { WtPrep m[26]; };

__global__ void wt_prep_kernel(WtPrepAll all, short* __restrict__ dst)
{
    const WtPrep p = all.m[blockIdx.y];
    int total = 128 * p.Kpad;
    int idx = blockIdx.x * 256 + threadIdx.x;
    if (idx >= total) return;
    int n = idx / p.Kpad, k = idx - n * p.Kpad;
    float v = (k < p.K) ? p.src[(size_t)k * 128 + n] : 0.f;
    dst[p.dstOff + idx] = (short)f2bf(v);
}

__global__ void zero_kernel(float4* __restrict__ p, long n4)
{
    long i = (long)blockIdx.x * blockDim.x + threadIdx.x;
    if (i < n4) p[i] = make_float4(0.f, 0.f, 0.f, 0.f);
}

// ---------------------------------------------------------------------------
extern "C" void kernel_launch(void* const* d_in, const int* in_sizes, int n_in,
                              void* d_out, int out_size, void* d_ws, size_t ws_size,
                              hipStream_t stream)
{
    const float* node_x   = (const float*)d_in[0];
    const float* edge_x   = (const float*)d_in[1];
    const float* enc_n_W0 = (const float*)d_in[2];
    const float* enc_n_b0 = (const float*)d_in[3];
    const float* enc_n_W1 = (const float*)d_in[4];
    const float* enc_n_b1 = (const float*)d_in[5];
    const float* enc_n_W2 = (const float*)d_in[6];
    const float* enc_n_b2 = (const float*)d_in[7];
    const float* enc_n_g  = (const float*)d_in[8];
    const float* enc_n_be = (const float*)d_in[9];
    const float* enc_e_W0 = (const float*)d_in[10];
    const float* enc_e_b0 = (const float*)d_in[11];
    const float* enc_e_W1 = (const float*)d_in[12];
    const float* enc_e_b1 = (const float*)d_in[13];
    const float* enc_e_W2 = (const float*)d_in[14];
    const float* enc_e_b2 = (const float*)d_in[15];
    const float* enc_e_g  = (const float*)d_in[16];
    const float* enc_e_be = (const float*)d_in[17];
    const float* gnb_e_W0 = (const float*)d_in[18];
    const float* gnb_e_b0 = (const float*)d_in[19];
    const float* gnb_e_W1 = (const float*)d_in[20];
    const float* gnb_e_b1 = (const float*)d_in[21];
    const float* gnb_e_W2 = (const float*)d_in[22];
    const float* gnb_e_b2 = (const float*)d_in[23];
    const float* gnb_e_g  = (const float*)d_in[24];
    const float* gnb_e_be = (const float*)d_in[25];
    const float* gnb_n_W0 = (const float*)d_in[26];
    const float* gnb_n_b0 = (const float*)d_in[27];
    const float* gnb_n_W1 = (const float*)d_in[28];
    const float* gnb_n_b1 = (const float*)d_in[29];
    const float* gnb_n_W2 = (const float*)d_in[30];
    const float* gnb_n_b2 = (const float*)d_in[31];
    const float* gnb_n_g  = (const float*)d_in[32];
    const float* gnb_n_be = (const float*)d_in[33];
    const float* dec_W0   = (const float*)d_in[34];
    const float* dec_b0   = (const float*)d_in[35];
    const float* dec_W1   = (const float*)d_in[36];
    const float* dec_b1   = (const float*)d_in[37];
    const float* dec_W2   = (const float*)d_in[38];
    const float* dec_b2   = (const float*)d_in[39];
    const int*   senders  = (const int*)d_in[40];
    const int*   receivers= (const int*)d_in[41];
    float* out = (float*)d_out;

    const int N = NN, E = EE;
    const int WT_TOTAL = (32 + 128 + 128 + 32 + 128 + 128 + 3 * (384 + 128 + 128 + 256 + 128 + 128)
                          + 128 + 128) * 128;   // shorts = 548864

    // ---- workspace layout: identical to round 6 (109.26 MB, known-good) ----
    float* nf   = (float*)d_ws;                      // N*128 f32
    float* agg  = nf + (size_t)N * 128;              // N*128 f32
    float* ef   = agg + (size_t)N * 128;             // E*128 f32
    short* nfbf = (short*)(ef + (size_t)E * 128);    // N*128 bf16
    short* wt   = nfbf + (size_t)N * 128;            // WT_TOTAL bf16
    int*   eList = (int*)(wt + WT_TOTAL);            // E ints (sorted path only)
    size_t need_sorted = (size_t)((char*)(eList + E) - (char*)d_ws);
    int* cnt    = (int*)agg;                          // transient overlay on agg
    int* cursor = cnt + N;

    const bool useSorted = (ws_size >= need_sorted);
    const int* eL = useSorted ? eList : nullptr;

    // ---- weight prep table ----
    WtPrepAll tbl;
    int nMat = 0, off = 0;
    int o_encn[3], o_ence[3], o_ge0[3], o_ge1[3], o_ge2[3], o_gn0[3], o_gn1[3], o_gn2[3], o_dec[2];
    auto add = [&](const float* src, int K, int Kpad) {
        tbl.m[nMat].src = src; tbl.m[nMat].K = K; tbl.m[nMat].Kpad = Kpad;
        tbl.m[nMat].dstOff = off;
        int r = off; off += 128 * Kpad; ++nMat; return r;
    };
    o_encn[0] = add(enc_n_W0, 12, 32);
    o_encn[1] = add(enc_n_W1, 128, 128);
    o_encn[2] = add(enc_n_W2, 128, 128);
    o_ence[0] = add(enc_e_W0, 7, 32);
    o_ence[1] = add(enc_e_W1, 128, 128);
    o_ence[2] = add(enc_e_W2, 128, 128);
    for (int s = 0; s < 3; ++s) {
        o_ge0[s] = add(gnb_e_W0 + (size_t)s * 384 * 128, 384, 384);
        o_ge1[s] = add(gnb_e_W1 + (size_t)s * 128 * 128, 128, 128);
        o_ge2[s] = add(gnb_e_W2 + (size_t)s * 128 * 128, 128, 128);
        o_gn0[s] = add(gnb_n_W0 + (size_t)s * 256 * 128, 256, 256);
        o_gn1[s] = add(gnb_n_W1 + (size_t)s * 128 * 128, 128, 128);
        o_gn2[s] = add(gnb_n_W2 + (size_t)s * 128 * 128, 128, 128);
    }
    o_dec[0] = add(dec_W0, 128, 128);
    o_dec[1] = add(dec_W1, 128, 128);

    wt_prep_kernel<<<dim3(192, 26), 256, 0, stream>>>(tbl, wt);

    if (useSorted) {
        zero_i<<<dim3((N + 255) / 256), 256, 0, stream>>>(cnt, N);
        csr_count<<<dim3((E + 255) / 256), 256, 0, stream>>>(receivers, cnt, E);
        csr_scan<<<dim3(1), 256, 0, stream>>>(cnt, cursor, N);
        csr_fill<<<dim3((E + 255) / 256), 256, 0, stream>>>(receivers, cursor, eList, E);
    }

    const dim3 gN((N + 127) / 128), gE(E / 128);

    // ---- encoders ----
    gnn_mlp<<<gN, 256, 0, stream>>>(wt + o_encn[0], 32, wt + o_encn[1], wt + o_encn[2],
        enc_n_b0, enc_n_b1, enc_n_b2, enc_n_g, enc_n_be,
        node_x, 12, nullptr, nullptr, nullptr, nullptr, nullptr, nullptr,
        nf, nfbf, nullptr, nullptr, N, 0, 0);
    gnn_mlp<<<gE, 256, 0, stream>>>(wt + o_ence[0], 32, wt + o_ence[1], wt + o_ence[2],
        enc_e_b0, enc_e_b1, enc_e_b2, enc_e_g, enc_e_be,
        edge_x, 7, nullptr, nullptr, nullptr, nullptr, nullptr, nullptr,
        ef, nullptr, nullptr, nullptr, E, 0, 0);

    // ---- 3 message-passing steps ----
    for (int s = 0; s < 3; ++s) {
        const float* eb0 = gnb_e_b0 + (size_t)s * 128;
        const float* eb1 = gnb_e_b1 + (size_t)s * 128;
        const float* eb2 = gnb_e_b2 + (size_t)s * 128;
        const float* eg  = gnb_e_g  + (size_t)s * 128;
        const float* ebe = gnb_e_be + (size_t)s * 128;
        const float* nb0 = gnb_n_b0 + (size_t)s * 128;
        const float* nb1 = gnb_n_b1 + (size_t)s * 128;
        const float* nb2 = gnb_n_b2 + (size_t)s * 128;
        const float* ng  = gnb_n_g  + (size_t)s * 128;
        const float* nbe = gnb_n_be + (size_t)s * 128;

        zero_kernel<<<dim3((N * 32 + 255) / 256), 256, 0, stream>>>((float4*)agg, (long)N * 32);
        gnn_mlp<<<gE, 256, 0, stream>>>(wt + o_ge0[s], 384, wt + o_ge1[s], wt + o_ge2[s],
            eb0, eb1, eb2, eg, ebe,
            nullptr, 0, nfbf, ef, nullptr, eL, senders, receivers,
            ef, nullptr, agg, nullptr, E, 1, 1);
        gnn_mlp<<<gN, 256, 0, stream>>>(wt + o_gn0[s], 256, wt + o_gn1[s], wt + o_gn2[s],
            nb0, nb1, nb2, ng, nbe,
            nullptr, 0, nfbf, nullptr, agg, nullptr, nullptr, nullptr,
            nf, nfbf, nullptr, nullptr, N, 2, 1);
    }

    // ---- decoder ----
    gnn_mlp<<<gN, 256, 0, stream>>>(wt + o_dec[0], 128, wt + o_dec[1], nullptr,
        dec_b0, dec_b1, dec_b2, nullptr, nullptr,
        dec_W2, 0, nfbf, nullptr, nullptr, nullptr, nullptr, nullptr,
        nullptr, nullptr, nullptr, out, N, 3, 0);
}